// Round 1
// baseline (281.219 us; speedup 1.0000x reference)
//
#include <hip/hip_runtime.h>
#include <hip/hip_bf16.h>
#include <stdint.h>

#define N_NODES 50000
#define KNB 32
#define DIM 256

typedef short s8v __attribute__((ext_vector_type(8)));
typedef float f4v __attribute__((ext_vector_type(4)));
typedef unsigned short u16;

__device__ inline float bf2f(u16 h) {
    unsigned int u = ((unsigned int)h) << 16;
    return __builtin_bit_cast(float, u);
}
__device__ inline u16 f2bf(float f) {
    unsigned int u = __builtin_bit_cast(unsigned int, f);
    unsigned int r = (u + 0x7fffu + ((u >> 16) & 1u)) >> 16;
    return (u16)r;
}

// ---------------- kernel 1: convert x -> bf16, weights -> bf16 transposed ----
__global__ __launch_bounds__(256) void k_convert(
    const float* __restrict__ x, const float* __restrict__ Wc,
    const float* __restrict__ Wn, u16* __restrict__ xb,
    u16* __restrict__ Wct, u16* __restrict__ Wnt)
{
    int64_t tid = (int64_t)blockIdx.x * blockDim.x + threadIdx.x;
    int64_t stride = (int64_t)gridDim.x * blockDim.x;
    const int64_t nx4 = (int64_t)N_NODES * DIM / 4;
    for (int64_t i = tid; i < nx4; i += stride) {
        float4 v = ((const float4*)x)[i];
        ushort4 o;
        o.x = f2bf(v.x); o.y = f2bf(v.y); o.z = f2bf(v.z); o.w = f2bf(v.w);
        ((ushort4*)xb)[i] = o;
    }
    for (int64_t i = tid; i < 256 * 256; i += stride) {
        int r = (int)(i >> 8), c = (int)(i & 255);   // W[r][c]
        Wct[c * 256 + r] = f2bf(Wc[i]);
        Wnt[c * 256 + r] = f2bf(Wn[i]);
    }
}

// ---------------- kernel 2: gather-sum neighbors (one wave per node) --------
// sb[n][d]  = bf16( (1/nh) * sum_k x[adj[n][k]][d] )
// esc[n][e] = (1/nh) * sum_k edge[n][k][e]
__global__ __launch_bounds__(256) void k_gather(
    const u16* __restrict__ xb, const int* __restrict__ adj,
    const float* __restrict__ edge, u16* __restrict__ sb,
    float* __restrict__ esc)
{
    int wave = threadIdx.x >> 6;
    int lane = threadIdx.x & 63;
    int n = blockIdx.x * 4 + wave;
    if (n >= N_NODES) return;

    int aidx = 0, valid = 0;
    if (lane < 32) {
        aidx = adj[n * 32 + lane];
        valid = (aidx != -1);
        if (aidx < 0) aidx += N_NODES;       // numpy-style wrap for padding
    }
    unsigned long long m = __ballot(lane < 32 && valid);
    int nh = __popcll(m);
    float inv = 1.0f / fmaxf((float)nh, 1.0f);

    // edge row: exactly 64 floats [K=32][2]; lane = k*2+d
    float ev = edge[(int64_t)n * 64 + lane];
    ev += __shfl_xor(ev, 2);
    ev += __shfl_xor(ev, 4);
    ev += __shfl_xor(ev, 8);
    ev += __shfl_xor(ev, 16);
    ev += __shfl_xor(ev, 32);
    if (lane < 2) esc[n * 2 + lane] = ev * inv;

    float a0 = 0.f, a1 = 0.f, a2 = 0.f, a3 = 0.f;
    int col = lane * 4;                      // 64 lanes x 4 bf16 = 256
    #pragma unroll 4
    for (int k = 0; k < 32; ++k) {
        int idx = __shfl(aidx, k);
        ushort4 v = *(const ushort4*)(xb + (int64_t)idx * DIM + col);
        a0 += bf2f(v.x); a1 += bf2f(v.y); a2 += bf2f(v.z); a3 += bf2f(v.w);
    }
    ushort4 o;
    o.x = f2bf(a0 * inv); o.y = f2bf(a1 * inv);
    o.z = f2bf(a2 * inv); o.w = f2bf(a3 * inv);
    *(ushort4*)(sb + (int64_t)n * DIM + col) = o;
}

// ---------------- kernel 3: fused K=512 bf16 MFMA GEMM + epilogue ----------
// out[n][j] = relu( xb[n]@Wct[j] + sb[n]@Wnt[j] + esc[n]·We[:,j] + b[j] )
__global__ __launch_bounds__(256) void k_gemm(
    const u16* __restrict__ xb, const u16* __restrict__ sb,
    const u16* __restrict__ Wct, const u16* __restrict__ Wnt,
    const float* __restrict__ esc, const float* __restrict__ We,
    const float* __restrict__ bias, float* __restrict__ out)
{
    int wv = threadIdx.x >> 6, lane = threadIdx.x & 63;
    int rowbase = blockIdx.x * 64 + wv * 16;

    int arow = rowbase + (lane & 15);
    if (arow >= N_NODES) arow = N_NODES - 1;   // clamp; stores guarded below
    int kgrp = (lane >> 4) * 8;                // k-chunk within 32

    f4v acc[16];
    #pragma unroll
    for (int i = 0; i < 16; ++i) acc[i] = (f4v){0.f, 0.f, 0.f, 0.f};

    const u16* aA = xb + (int64_t)arow * 256;
    const u16* aS = sb + (int64_t)arow * 256;

    #pragma unroll
    for (int ks = 0; ks < 16; ++ks) {
        const u16* Abase = (ks < 8) ? aA : aS;
        const u16* Bbase = (ks < 8) ? Wct : Wnt;
        int klocal = (ks & 7) * 32 + kgrp;
        s8v a = *(const s8v*)(Abase + klocal);
        #pragma unroll
        for (int nf = 0; nf < 16; ++nf) {
            int colf = nf * 16 + (lane & 15);
            s8v b = *(const s8v*)(Bbase + colf * 256 + klocal);
            acc[nf] = __builtin_amdgcn_mfma_f32_16x16x32_bf16(a, b, acc[nf], 0, 0, 0);
        }
    }

    // C/D layout: col = lane&15, row = (lane>>4)*4 + reg   [verified m89/m91]
    int r0 = rowbase + (lane >> 4) * 4;
    int col0 = lane & 15;
    float e0[4], e1[4];
    #pragma unroll
    for (int r = 0; r < 4; ++r) {
        int row = r0 + r; if (row >= N_NODES) row = N_NODES - 1;
        e0[r] = esc[row * 2];
        e1[r] = esc[row * 2 + 1];
    }
    #pragma unroll
    for (int nf = 0; nf < 16; ++nf) {
        int colj = nf * 16 + col0;
        float bc = bias[colj];
        float w0 = We[colj];
        float w1 = We[256 + colj];
        #pragma unroll
        for (int r = 0; r < 4; ++r) {
            int row = r0 + r;
            if (row < N_NODES) {
                float v = acc[nf][r] + bc + e0[r] * w0 + e1[r] * w1;
                out[(int64_t)row * 256 + colj] = fmaxf(v, 0.0f);
            }
        }
    }
}

extern "C" void kernel_launch(void* const* d_in, const int* in_sizes, int n_in,
                              void* d_out, int out_size, void* d_ws, size_t ws_size,
                              hipStream_t stream) {
    const float* x    = (const float*)d_in[0];
    const int*   adj  = (const int*)d_in[1];
    const float* edge = (const float*)d_in[2];
    const float* Wc   = (const float*)d_in[3];
    const float* Wn   = (const float*)d_in[4];
    const float* We   = (const float*)d_in[5];
    // d_in[6] = q : dead (softmax over size-1 axis == 1.0)
    const float* bias = (const float*)d_in[7];
    float* out = (float*)d_out;

    char* ws = (char*)d_ws;
    const int64_t XB_OFF  = 0;                       // N*256 bf16 = 25.6 MB
    const int64_t SB_OFF  = 25600000;                // N*256 bf16 = 25.6 MB
    const int64_t ESC_OFF = 51200000;                // N*2 f32    = 0.4 MB
    const int64_t WCT_OFF = 51600128;                // 256*256 bf16
    const int64_t WNT_OFF = 51731200;                // 256*256 bf16
    u16*   xb  = (u16*)(ws + XB_OFF);
    u16*   sb  = (u16*)(ws + SB_OFF);
    float* esc = (float*)(ws + ESC_OFF);
    u16*   Wct = (u16*)(ws + WCT_OFF);
    u16*   Wnt = (u16*)(ws + WNT_OFF);

    k_convert<<<2048, 256, 0, stream>>>(x, Wc, Wn, xb, Wct, Wnt);
    k_gather<<<(N_NODES + 3) / 4, 256, 0, stream>>>(xb, adj, edge, sb, esc);
    k_gemm<<<(N_NODES + 63) / 64, 256, 0, stream>>>(xb, sb, Wct, Wnt, esc, We, bias, out);
}

// Round 2
// 157.524 us; speedup vs baseline: 1.7852x; 1.7852x over previous
//
#include <hip/hip_runtime.h>
#include <hip/hip_bf16.h>
#include <stdint.h>

#define N_NODES 50000
#define KNB 32
#define DIM 256

typedef short s8v __attribute__((ext_vector_type(8)));
typedef float f4v __attribute__((ext_vector_type(4)));
typedef unsigned short u16;

__device__ inline float bf2f(u16 h) {
    unsigned int u = ((unsigned int)h) << 16;
    return __builtin_bit_cast(float, u);
}
__device__ inline u16 f2bf(float f) {
    unsigned int u = __builtin_bit_cast(unsigned int, f);
    unsigned int r = (u + 0x7fffu + ((u >> 16) & 1u)) >> 16;
    return (u16)r;
}

#define GLOAD16(gp, lp) __builtin_amdgcn_global_load_lds( \
    (const __attribute__((address_space(1))) unsigned int*)(gp), \
    (__attribute__((address_space(3))) unsigned int*)(lp), 16, 0, 0)

// ---------------- kernel 1: convert x -> bf16, weights -> bf16 transposed ----
__global__ __launch_bounds__(256) void k_convert(
    const float* __restrict__ x, const float* __restrict__ Wc,
    const float* __restrict__ Wn, u16* __restrict__ xb,
    u16* __restrict__ Wct, u16* __restrict__ Wnt)
{
    int64_t tid = (int64_t)blockIdx.x * blockDim.x + threadIdx.x;
    int64_t stride = (int64_t)gridDim.x * blockDim.x;
    const int64_t nx4 = (int64_t)N_NODES * DIM / 4;
    for (int64_t i = tid; i < nx4; i += stride) {
        float4 v = ((const float4*)x)[i];
        ushort4 o;
        o.x = f2bf(v.x); o.y = f2bf(v.y); o.z = f2bf(v.z); o.w = f2bf(v.w);
        ((ushort4*)xb)[i] = o;
    }
    for (int64_t i = tid; i < 256 * 256; i += stride) {
        int r = (int)(i >> 8), c = (int)(i & 255);   // W[r][c]
        Wct[c * 256 + r] = f2bf(Wc[i]);
        Wnt[c * 256 + r] = f2bf(Wn[i]);
    }
}

// ---------------- kernel 2: gather-sum neighbors (one wave per node) --------
// sb[n][d]  = bf16( (1/nh) * sum_k x[adj[n][k]][d] )
// esc[n][e] = (1/nh) * sum_k edge[n][k][e]
__global__ __launch_bounds__(256) void k_gather(
    const u16* __restrict__ xb, const int* __restrict__ adj,
    const float* __restrict__ edge, u16* __restrict__ sb,
    float* __restrict__ esc)
{
    int wave = threadIdx.x >> 6;
    int lane = threadIdx.x & 63;
    int n = blockIdx.x * 4 + wave;
    if (n >= N_NODES) return;

    int aidx = 0, valid = 0;
    if (lane < 32) {
        aidx = adj[n * 32 + lane];
        valid = (aidx != -1);
        if (aidx < 0) aidx += N_NODES;       // numpy-style wrap for padding
    }
    unsigned long long m = __ballot(lane < 32 && valid);
    int nh = __popcll(m);
    float inv = 1.0f / fmaxf((float)nh, 1.0f);

    // edge row: exactly 64 floats [K=32][2]; lane = k*2+d
    float ev = edge[(int64_t)n * 64 + lane];
    ev += __shfl_xor(ev, 2);
    ev += __shfl_xor(ev, 4);
    ev += __shfl_xor(ev, 8);
    ev += __shfl_xor(ev, 16);
    ev += __shfl_xor(ev, 32);
    if (lane < 2) esc[n * 2 + lane] = ev * inv;

    // 16-B loads: lane handles seg = lane&31 (16B of the 512B row),
    // half = lane>>5 selects which of 2 neighbor rows per iteration.
    int seg = lane & 31;
    int half = lane >> 5;
    float acc[8] = {0.f, 0.f, 0.f, 0.f, 0.f, 0.f, 0.f, 0.f};
    #pragma unroll 4
    for (int it = 0; it < 16; ++it) {
        int idx = __shfl(aidx, it * 2 + half);
        s8v v = *(const s8v*)(xb + (int64_t)idx * DIM + seg * 8);
        #pragma unroll
        for (int j = 0; j < 8; ++j) acc[j] += bf2f((u16)v[j]);
    }
    #pragma unroll
    for (int j = 0; j < 8; ++j) acc[j] += __shfl_xor(acc[j], 32);

    if (lane < 32) {
        s8v o;
        #pragma unroll
        for (int j = 0; j < 8; ++j) o[j] = (short)f2bf(acc[j] * inv);
        *(s8v*)(sb + (int64_t)n * DIM + seg * 8) = o;
    }
}

// ---------------- kernel 3: LDS-staged K=512 bf16 MFMA GEMM + epilogue ------
// out[n][j] = relu( xb[n]@Wct[j] + sb[n]@Wnt[j] + esc[n]·We[:,j] + b[j] )
// BM=128, BN=128, BK=64; A = concat(xb,sb) along K; B = concat(Wct,Wnt).
// Tiles stored [row][64] bf16 with seg XOR-swizzle (seg ^= row&7, 16B segs),
// applied on the GLOBAL source (linear LDS dest for global_load_lds, rule 21).
__device__ inline void stage_tile(u16* tile, const u16* src, int row0, int rowmax,
                                  int kboEl, int wv, int lane)
{
    #pragma unroll
    for (int c = 0; c < 4; ++c) {
        int idxbase = c * 256 + wv * 64;       // wave-uniform
        int idx = idxbase + lane;
        int row = idx >> 3, seg = idx & 7;
        int gr = row0 + row; if (gr > rowmax) gr = rowmax;
        int srcseg = seg ^ (row & 7);
        const u16* g = src + (int64_t)gr * 256 + kboEl + srcseg * 8;
        GLOAD16(g, (char*)tile + idxbase * 16);
    }
}

__global__ __launch_bounds__(256) void k_gemm(
    const u16* __restrict__ xb, const u16* __restrict__ sb,
    const u16* __restrict__ Wct, const u16* __restrict__ Wnt,
    const float* __restrict__ esc, const float* __restrict__ We,
    const float* __restrict__ bias, float* __restrict__ out)
{
    __shared__ u16 Atile[2][128 * 64];
    __shared__ u16 Btile[2][128 * 64];

    int wv = threadIdx.x >> 6, lane = threadIdx.x & 63;
    int wm = wv >> 1, wn = wv & 1;
    int bm = blockIdx.x >> 1;          // M-tile (391 tiles)
    int nt = blockIdx.x & 1;           // N-tile (2 tiles)
    int mrow0 = bm * 128;
    int ncol0 = nt * 128;

    f4v acc[4][4];
    #pragma unroll
    for (int m = 0; m < 4; ++m)
        #pragma unroll
        for (int n = 0; n < 4; ++n) acc[m][n] = (f4v){0.f, 0.f, 0.f, 0.f};

    // prologue: stage K-step 0 into buf 0
    stage_tile(Atile[0], xb, mrow0, N_NODES - 1, 0, wv, lane);
    stage_tile(Btile[0], Wct, ncol0, 255, 0, wv, lane);
    __syncthreads();

    int cur = 0;
    int lrow = wm * 64, lcol = wn * 64;
    int l15 = lane & 15, l4 = lane >> 4;

    for (int kb = 0; kb < 8; ++kb) {
        if (kb < 7) {
            int kn = kb + 1;
            const u16* As = (kn < 4) ? xb : sb;
            const u16* Bs = (kn < 4) ? Wct : Wnt;
            int kboEl = (kn & 3) * 64;
            stage_tile(Atile[cur ^ 1], As, mrow0, N_NODES - 1, kboEl, wv, lane);
            stage_tile(Btile[cur ^ 1], Bs, ncol0, 255, kboEl, wv, lane);
        }
        const u16* At = Atile[cur];
        const u16* Bt = Btile[cur];
        #pragma unroll
        for (int ks = 0; ks < 2; ++ks) {
            s8v af[4], bfr[4];
            #pragma unroll
            for (int m = 0; m < 4; ++m) {
                int row = lrow + m * 16 + l15;
                int kb16 = ((ks * 4 + l4) * 16) ^ ((row & 7) << 4);
                af[m] = *(const s8v*)((const char*)At + row * 128 + kb16);
            }
            #pragma unroll
            for (int n = 0; n < 4; ++n) {
                int col = lcol + n * 16 + l15;
                int kb16 = ((ks * 4 + l4) * 16) ^ ((col & 7) << 4);
                bfr[n] = *(const s8v*)((const char*)Bt + col * 128 + kb16);
            }
            #pragma unroll
            for (int m = 0; m < 4; ++m)
                #pragma unroll
                for (int n = 0; n < 4; ++n)
                    acc[m][n] = __builtin_amdgcn_mfma_f32_16x16x32_bf16(
                        af[m], bfr[n], acc[m][n], 0, 0, 0);
        }
        __syncthreads();
        cur ^= 1;
    }

    // epilogue: C/D layout col=lane&15, row=(lane>>4)*4+reg
    #pragma unroll
    for (int m = 0; m < 4; ++m) {
        int r0 = mrow0 + lrow + m * 16 + l4 * 4;
        float e0[4], e1[4];
        #pragma unroll
        for (int r = 0; r < 4; ++r) {
            int row = r0 + r; if (row >= N_NODES) row = N_NODES - 1;
            e0[r] = esc[row * 2];
            e1[r] = esc[row * 2 + 1];
        }
        #pragma unroll
        for (int n = 0; n < 4; ++n) {
            int col = ncol0 + lcol + n * 16 + l15;
            float bc = bias[col];
            float w0 = We[col];
            float w1 = We[256 + col];
            #pragma unroll
            for (int r = 0; r < 4; ++r) {
                int row = r0 + r;
                if (row < N_NODES) {
                    float v = acc[m][n][r] + bc + e0[r] * w0 + e1[r] * w1;
                    out[(int64_t)row * 256 + col] = fmaxf(v, 0.0f);
                }
            }
        }
    }
}

extern "C" void kernel_launch(void* const* d_in, const int* in_sizes, int n_in,
                              void* d_out, int out_size, void* d_ws, size_t ws_size,
                              hipStream_t stream) {
    const float* x    = (const float*)d_in[0];
    const int*   adj  = (const int*)d_in[1];
    const float* edge = (const float*)d_in[2];
    const float* Wc   = (const float*)d_in[3];
    const float* Wn   = (const float*)d_in[4];
    const float* We   = (const float*)d_in[5];
    // d_in[6] = q : dead (softmax over size-1 axis == 1.0)
    const float* bias = (const float*)d_in[7];
    float* out = (float*)d_out;

    char* ws = (char*)d_ws;
    const int64_t XB_OFF  = 0;                       // N*256 bf16 = 25.6 MB
    const int64_t SB_OFF  = 25600000;                // N*256 bf16 = 25.6 MB
    const int64_t ESC_OFF = 51200000;                // N*2 f32    = 0.4 MB
    const int64_t WCT_OFF = 51600128;                // 256*256 bf16
    const int64_t WNT_OFF = 51731200;                // 256*256 bf16
    u16*   xb  = (u16*)(ws + XB_OFF);
    u16*   sb  = (u16*)(ws + SB_OFF);
    float* esc = (float*)(ws + ESC_OFF);
    u16*   Wct = (u16*)(ws + WCT_OFF);
    u16*   Wnt = (u16*)(ws + WNT_OFF);

    k_convert<<<2048, 256, 0, stream>>>(x, Wc, Wn, xb, Wct, Wnt);
    k_gather<<<(N_NODES + 3) / 4, 256, 0, stream>>>(xb, adj, edge, sb, esc);
    k_gemm<<<(N_NODES + 127) / 128 * 2, 256, 0, stream>>>(xb, sb, Wct, Wnt, esc, We, bias, out);
}